// Round 6
// baseline (86.005 us; speedup 1.0000x reference)
//
#include <hip/hip_runtime.h>
#include <math.h>

#define RAD 5
#define SIDE 80
#define SLAB 6400      // 80*80
#define VOL 512000     // 80^3
#define NCH 8          // N*K
#define NCLS 4
#define Q 20           // float4/ushort4 columns per 80-elem row
#define TW 40          // K1 tile extent along w (halo 1.25x; 1280 blocks = 5/CU resident)
#define NT 2           // w-tiles per axis (80/40)
#define C1 (SIDE*NT)           // 160 K1 slots per channel
#define NBLK1 (NCH*C1)         // 1280 K1 blocks
#define TBS 22                 // tB row stride in float4
#define NBLK2 1280             // K2 blocks: (c, w, h-half) = 8*80*2, 5/CU exact
#define CPB 160                // K2 blocks per channel
#define SBS 84                 // K2 LDS row stride in floats (21 float4, 336 B)

// exp(-t^2/32) for t=-5..5 (unnormalized Gaussian, symmetric)
__constant__ float GW[11] = {
    0.45783336177161427f, 0.6065306597126334f, 0.7548396019890073f,
    0.8824969025845955f,  0.969233234476344f,  1.0f,
    0.969233234476344f,   0.8824969025845955f, 0.7548396019890073f,
    0.6065306597126334f,  0.45783336177161427f};

// Module-scope scratch. Slot-based cross-kernel dataflow ONLY:
// R8: device atomics+fences = +100 µs/kernel; R7: grid.sync = +550 µs.
// Kernel boundaries are the only sync primitive used.
// R12 lesson: residency-critical kernels need LDS small enough for 5 blocks/CU.
__device__ unsigned short g_bufT[(size_t)NCH * VOL];  // bf16 conv'd labels, [c][w][h][d]
__device__ float2 g_part1[NBLK1];             // {S_ip, S_p} per K1 block
__device__ float2 g_part2[NBLK2];             // {num, den} per K2 block

__device__ __forceinline__ unsigned short f2bf(float f) {
    unsigned u = __float_as_uint(f);
    u += 0x7FFFu + ((u >> 16) & 1u);          // round-to-nearest-even
    return (unsigned short)(u >> 16);
}
__device__ __forceinline__ float bf2f(unsigned short h) {
    return __uint_as_float((unsigned)h << 16);
}

// K1: per (c, h, w-tile40): d-conv via register window from global,
// fused channel sums, w-conv via LDS gather, transposed bf16 store to g_bufT.
// R15 phase A: one thread = one (row, 16-output d-group). a[32] window from
// 8 guarded b128 loads -> 0.5 loads/output (was 1.25), one item/thread (was 4),
// single load-latency exposure. FMA count unchanged. Grid/LDS/phase B unchanged.
__global__ void __launch_bounds__(256) convdw_sums_kernel(
        const float* __restrict__ labels, const float* __restrict__ img) {
    const int tile = blockIdx.x;
    const int c   = tile / C1;
    const int rem = tile % C1;
    const int h   = rem / NT;
    const int w0  = (rem % NT) * TW;
    const int n   = c >> 2;

    __shared__ float4 tB[(TW + 10) * TBS];   // d-conv result rows w0-5..w0+TW+4
    __shared__ float sm[8];

    const float4* labc4 = (const float4*)(labels + ((size_t)c * SIDE + h) * SLAB);
    const float4* imgc4 = (const float4*)(img + ((size_t)n * SIDE + h) * SLAB);

    float sip = 0.f, sp = 0.f;
    if (threadIdx.x < 250) {                 // 50 rows x 5 d-groups, 1 item/thread
        const int r  = threadIdx.x / 5;      // staged row 0..49
        const int qg = threadIdx.x % 5;      // 16-output d-group 0..4
        const int w  = w0 - RAD + r;
        float a[32];                         // labels at d = 16qg-8 .. 16qg+23
        #pragma unroll
        for (int j = 0; j < 32; ++j) a[j] = 0.f;
        if ((unsigned)w < SIDE) {
            const float4* row = labc4 + (size_t)w * Q;
            #pragma unroll
            for (int j = 0; j < 8; ++j) {
                int ss = 4 * qg - 2 + j;
                if (ss >= 0 && ss < Q) {
                    float4 v = row[ss];
                    a[4 * j] = v.x; a[4 * j + 1] = v.y;
                    a[4 * j + 2] = v.z; a[4 * j + 3] = v.w;
                }
            }
            if (r >= RAD && r < RAD + TW) {  // central rows: fused channel sums
                #pragma unroll
                for (int jj = 0; jj < 4; ++jj) {
                    float4 v = imgc4[(size_t)w * Q + 4 * qg + jj];
                    sip += a[8 + 4 * jj] * v.x + a[9 + 4 * jj] * v.y +
                           a[10 + 4 * jj] * v.z + a[11 + 4 * jj] * v.w;
                    sp  += a[8 + 4 * jj] + a[9 + 4 * jj] +
                           a[10 + 4 * jj] + a[11 + 4 * jj];
                }
            }
        }
        // 4 output float4s: output d = 16qg+m at a[m+8]; tap t -> a[m+t+3]
        #pragma unroll
        for (int jj = 0; jj < 4; ++jj) {
            float s0 = 0.f, s1 = 0.f, s2 = 0.f, s3 = 0.f;
            #pragma unroll
            for (int t = 0; t < 11; ++t) {
                float g = GW[t];
                s0 += g * a[4 * jj + t + 3]; s1 += g * a[4 * jj + t + 4];
                s2 += g * a[4 * jj + t + 5]; s3 += g * a[4 * jj + t + 6];
            }
            tB[r * TBS + 4 * qg + jj] = make_float4(s0, s1, s2, s3);
        }
    }
    // block-reduce sums (same barrier covers tB completion + sm visibility)
    #pragma unroll
    for (int off = 32; off > 0; off >>= 1) {
        sip += __shfl_down(sip, off);
        sp  += __shfl_down(sp, off);
    }
    const int lane = threadIdx.x & 63;
    const int wid  = threadIdx.x >> 6;
    if (lane == 0) { sm[wid * 2] = sip; sm[wid * 2 + 1] = sp; }
    __syncthreads();
    if (threadIdx.x == 0)
        g_part1[tile] = make_float2(sm[0] + sm[2] + sm[4] + sm[6],
                                    sm[1] + sm[3] + sm[5] + sm[7]);
    // w-conv (11-tap LDS gather) + transposed bf16 ushort4 store
    ushort4* out4 = (ushort4*)g_bufT + ((size_t)c * VOL + (size_t)h * SIDE) / 4;
    for (int i = threadIdx.x; i < TW * Q; i += 256) {
        const int rl = i / Q, q = i - (i / Q) * Q;
        float sx = 0.f, sy = 0.f, sz = 0.f, sw = 0.f;
        #pragma unroll
        for (int t = 0; t < 11; ++t) {
            float g = GW[t];
            float4 v = tB[(rl + t) * TBS + q];
            sx += g * v.x; sy += g * v.y; sz += g * v.z; sw += g * v.w;
        }
        ushort4 o;
        o.x = f2bf(sx); o.y = f2bf(sy); o.z = f2bf(sz); o.w = f2bf(sw);
        out4[(size_t)(w0 + rl) * (SLAB / 4) + q] = o;
    }
}

// K2 (R14 winner, verbatim): block = (c, w, h-half). Stage the contiguous
// g_bufT[c][w][hh0-5..hh0+44][:] chunk (8 KB) into LDS as f32 ONCE
// (coalesced, 1.25x halo vs per-thread 3.5x window redundancy;
// bf16 cvt amortized to staging), h-conv from LDS, fused weights + dot.
// 1280 blocks = 5/CU exact; LDS 16.8 KB -> residency not limiting.
__global__ void __launch_bounds__(256) convh_dot_kernel(
        const float* __restrict__ labels, const float* __restrict__ img) {
    const int c   = blockIdx.x / CPB;
    const int rw  = blockIdx.x % CPB;
    const int w   = rw >> 1;
    const int hh0 = (rw & 1) * 40;
    const int n   = c >> 2;

    __shared__ float sB[50 * SBS];   // f32 window rows hh0-5..hh0+44
    __shared__ float sm[8];
    const int lane = threadIdx.x & 63;
    const int wid  = threadIdx.x >> 6;

    // oldest loads: mean partials (1 per thread, C1=160)
    float a = 0.f, b = 0.f;
    if (threadIdx.x < C1) {
        float2 p = g_part1[c * C1 + threadIdx.x];
        a = p.x; b = p.y;
    }

    // stage: contiguous bf16 chunk -> f32 LDS rows (zero-pad OOB halo)
    const ushort4* src = (const ushort4*)g_bufT + ((size_t)c * VOL + (size_t)w * SLAB) / 4;
    for (int i = threadIdx.x; i < 50 * Q; i += 256) {
        const int row = i / Q, s = i - (i / Q) * Q;
        const int hh = hh0 - RAD + row;
        float4 v = make_float4(0.f, 0.f, 0.f, 0.f);
        if ((unsigned)hh < SIDE) {
            ushort4 u = src[hh * Q + s];
            v = make_float4(bf2f(u.x), bf2f(u.y), bf2f(u.z), bf2f(u.w));
        }
        *(float4*)&sB[row * SBS + s * 4] = v;
    }

    // mean reduce (only needs the g_part1 loads)
    #pragma unroll
    for (int off = 32; off > 0; off >>= 1) {
        a += __shfl_down(a, off);
        b += __shfl_down(b, off);
    }
    if (lane == 0) { sm[wid * 2] = a; sm[wid * 2 + 1] = b; }
    __syncthreads();   // covers sB staging + sm visibility
    const float mean = (sm[0] + sm[2] + sm[4] + sm[6]) /
                       (sm[1] + sm[3] + sm[5] + sm[7] + 5.12f);   // VOL*EPS_MEAN

    // h-conv from LDS + fused weights + dot.  800 items = (40 h) x (20 q)
    const float4* labp4 = (const float4*)labels + (size_t)c * (VOL / 4);
    const float4* imgp4 = (const float4*)img + (size_t)n * (VOL / 4);
    float num = 0.f, den = 0.f;
    for (int i = threadIdx.x; i < TW * Q; i += 256) {
        const int hl = i / Q, q = i - (i / Q) * Q;
        const int h  = hh0 + hl;
        float sx = 0.f, sy = 0.f, sz = 0.f, sw = 0.f;
        #pragma unroll
        for (int t = 0; t < 11; ++t) {
            float g = GW[t];
            float4 v = *(const float4*)&sB[(hl + t) * SBS + q * 4];
            sx += g * v.x; sy += g * v.y; sz += g * v.z; sw += g * v.w;
        }
        const int li = h * (SLAB / 4) + w * Q + q;
        float4 l = labp4[li];
        float4 v = imgp4[li];
        float d0 = v.x - mean, d1 = v.y - mean, d2 = v.z - mean, d3 = v.w - mean;
        float q0 = d0 * d0, q1 = d1 * d1, q2 = d2 * d2, q3 = d3 * d3;
        float e0 = __expf(-q0 * q0), e1 = __expf(-q1 * q1);
        float e2 = __expf(-q2 * q2), e3 = __expf(-q3 * q3);
        num += sx * l.x * e0 + sy * l.y * e1 + sz * l.z * e2 + sw * l.w * e3;
        den += sx * e0 + sy * e1 + sz * e2 + sw * e3;
    }
    #pragma unroll
    for (int off = 32; off > 0; off >>= 1) {
        num += __shfl_down(num, off);
        den += __shfl_down(den, off);
    }
    __syncthreads();   // all threads done reading sm (mean) before reuse
    if (lane == 0) { sm[wid * 2] = num; sm[wid * 2 + 1] = den; }
    __syncthreads();
    if (threadIdx.x == 0)
        g_part2[blockIdx.x] = make_float2(sm[0] + sm[2] + sm[4] + sm[6],
                                          sm[1] + sm[3] + sm[5] + sm[7]);
}

// K3: reduce K2's per-block partials -> per-channel ratio -> loss scalar.
// Wave-parallel over channels (4 waves x 2 ch, 1 barrier). CPB=160.
__global__ void __launch_bounds__(256) final_kernel(float* __restrict__ out) {
    __shared__ float cn[NCH], cd[NCH];
    const int lane = threadIdx.x & 63;
    const int wid  = threadIdx.x >> 6;
    #pragma unroll
    for (int cc = 0; cc < 2; ++cc) {
        const int c = wid * 2 + cc;
        float a = 0.f, b = 0.f;
        for (int t = lane; t < CPB; t += 64) {
            float2 p = g_part2[c * CPB + t];
            a += p.x; b += p.y;
        }
        #pragma unroll
        for (int off = 32; off > 0; off >>= 1) {
            a += __shfl_down(a, off);
            b += __shfl_down(b, off);
        }
        if (lane == 0) { cn[c] = a; cd[c] = b; }
    }
    __syncthreads();
    if (threadIdx.x == 0) {
        float loss = 0.f;
        for (int k = 0; k < NCLS; ++k) {
            float r0 = cn[k]        / (cd[k]        + 1e-6f);
            float r1 = cn[NCLS + k] / (cd[NCLS + k] + 1e-6f);
            loss += 0.5f * (fabsf(r0) + fabsf(r1));   // mean over N=2, sum over K
        }
        out[0] = (float)NCLS - loss;
    }
}

extern "C" void kernel_launch(void* const* d_in, const int* in_sizes, int n_in,
                              void* d_out, int out_size, void* d_ws, size_t ws_size,
                              hipStream_t stream) {
    const float* labels = (const float*)d_in[0];   // (2,4,80,80,80) f32
    const float* img    = (const float*)d_in[1];   // (2,1,80,80,80) f32
    float* out = (float*)d_out;                    // 1 float
    (void)d_ws; (void)ws_size;                     // module-scope scratch

    hipLaunchKernelGGL(convdw_sums_kernel, dim3(NBLK1), dim3(256), 0, stream, labels, img);
    hipLaunchKernelGGL(convh_dot_kernel,   dim3(NBLK2), dim3(256), 0, stream, labels, img);
    hipLaunchKernelGGL(final_kernel,       dim3(1),     dim3(256), 0, stream, out);
}